// Round 6
// baseline (185.033 us; speedup 1.0000x reference)
//
#include <hip/hip_runtime.h>
#include <hip/hip_bf16.h>
#include <math.h>

#define B_ 4
#define T_ 4096
#define E_ 1024
#define H_ 64
#define NQT2 32      // T_/128 big q-tiles
#define NCHA 8       // passA chunks of 512 keys
#define KCHA 512
#define KCHB 256     // passB chunk size
#define TILESB 272   // per-batch live causal (128q x 256k) tiles: sum ceil((qt+1)/2)

using bf16x8 = __attribute__((ext_vector_type(8))) short;
using f32x4  = __attribute__((ext_vector_type(4))) float;

__device__ inline short f2bf_rn(float f) {
  return (short)((__builtin_bit_cast(unsigned, f) + 0x8000u) >> 16);
}
__device__ inline unsigned pack2(float a, float b) {  // bf16x2 {lo=a, hi=b}, RN
  const unsigned ua = __builtin_bit_cast(unsigned, a) + 0x8000u;
  const unsigned ub = __builtin_bit_cast(unsigned, b) + 0x8000u;
  return (ua >> 16) | (ub & 0xFFFF0000u);
}
__device__ inline bf16x8 pack8(float4 x0, float4 x1) {
  union { bf16x8 v; unsigned u[4]; } r;
  r.u[0] = pack2(x0.x, x0.y); r.u[1] = pack2(x0.z, x0.w);
  r.u[2] = pack2(x1.x, x1.y); r.u[3] = pack2(x1.z, x1.w);
  return r.v;
}
__device__ inline float bf2f(short s) {
  unsigned u = ((unsigned)(unsigned short)s) << 16;
  return __builtin_bit_cast(float, u);
}

// ---------- W transpose+convert: wt[mat*64+n][k] = W[k][n] (bf16) ----------
__global__ __launch_bounds__(256)
void wtconv_kernel(const float* __restrict__ wq, const float* __restrict__ wk,
                   const float* __restrict__ wv, short* __restrict__ wt) {
  const int row = blockIdx.x;          // 0..191
  const int mat = row >> 6, n = row & 63;
  const float* W = (mat == 0) ? wq : (mat == 1) ? wk : wv;
  for (int k = threadIdx.x; k < E_; k += 256)
    wt[(size_t)row * E_ + k] = f2bf_rn(W[(size_t)k * H_ + n]);
}

// ---------- QKV projection: single pass over x ----------
__global__ __launch_bounds__(256)
void proj_kernel(const float* __restrict__ x, const short* __restrict__ wt,
                 short* __restrict__ Qb, short* __restrict__ Kb,
                 short* __restrict__ Vt) {
  const int q0 = blockIdx.x * 32;
  const int t = threadIdx.x;
  const int wave = t >> 6, lane = t & 63, g = lane >> 4, l15 = lane & 15;
  const int qsub = wave >> 1, ch = wave & 1;
  const int arow = q0 + qsub * 16 + l15;
  f32x4 acc[6] = {{0,0,0,0},{0,0,0,0},{0,0,0,0},{0,0,0,0},{0,0,0,0},{0,0,0,0}};
#pragma unroll 2
  for (int k0 = 0; k0 < E_; k0 += 32) {
    const float* xp = x + (size_t)arow * E_ + k0 + 8 * g;
    const float4 x0 = *(const float4*)xp;
    const float4 x1 = *(const float4*)(xp + 4);
    const bf16x8 av = pack8(x0, x1);
#pragma unroll
    for (int n = 0; n < 6; ++n) {
      const int ntg = ch * 6 + n;
      const bf16x8 bfr = *(const bf16x8*)&wt[(size_t)(ntg*16 + l15) * E_ + k0 + 8*g];
      acc[n] = __builtin_amdgcn_mfma_f32_16x16x32_bf16(av, bfr, acc[n], 0, 0, 0);
    }
  }
#pragma unroll
  for (int n = 0; n < 6; ++n) {
    const int ntg = ch * 6 + n;
    const int mat = ntg >> 2;
    const int h = (ntg & 3) * 16 + l15;
#pragma unroll
    for (int r = 0; r < 4; ++r) {
      const int q = q0 + qsub * 16 + 4 * g + r;
      const short v = f2bf_rn(acc[n][r]);
      if (mat == 0)      Qb[(size_t)q * H_ + h] = v;
      else if (mat == 1) Kb[(size_t)q * H_ + h] = v;
      else               Vt[((size_t)(q >> 12) * H_ + h) * T_ + (q & (T_ - 1))] = v;
    }
  }
}

// ---------- pass A: partial Z over a 512-key chunk, 128-q blocks ----------
// 4 waves x 32q each; wave covers all 512 keys in 32-key steps; no LDS/sync.
__global__ __launch_bounds__(256, 4)
void passA_kernel(const short* __restrict__ Qb, const short* __restrict__ Kb,
                  float* __restrict__ Zp) {
  const int qt = blockIdx.x, c = blockIdx.y, b = blockIdx.z;
  const int t = threadIdx.x;
  const int w = t >> 6, lane = t & 63, g = lane >> 4, l15 = lane & 15;
  const int qbase = qt * 128 + w * 32;
  const short* Qp = Qb + (size_t)b * T_ * H_;
  const short* Kp = Kb + (size_t)b * T_ * H_;
  bf16x8 aq[2][2];
#pragma unroll
  for (int qs = 0; qs < 2; ++qs)
#pragma unroll
    for (int h = 0; h < 2; ++h)
      aq[qs][h] = *(const bf16x8*)&Qp[(size_t)(qbase + qs*16 + l15) * H_ + h*32 + 8*g];
  const int krow = ((l15 >> 2) << 3) + (l15 & 3);   // sigma(l15)
  float z0 = 0.f, z1 = 0.f;
  const int c0 = c * KCHA;
  for (int kt = c0; kt < c0 + KCHA; kt += 32) {
    const short* kr = Kp + (size_t)(kt + krow) * H_;
    const bf16x8 ak00 = *(const bf16x8*)(kr + 8 * g);
    const bf16x8 ak01 = *(const bf16x8*)(kr + 32 + 8 * g);
    const bf16x8 ak10 = *(const bf16x8*)(kr + 4 * H_ + 8 * g);
    const bf16x8 ak11 = *(const bf16x8*)(kr + 4 * H_ + 32 + 8 * g);
    f32x4 s00 = {0,0,0,0}, s01 = {0,0,0,0}, s10 = {0,0,0,0}, s11 = {0,0,0,0};
    s00 = __builtin_amdgcn_mfma_f32_16x16x32_bf16(ak00, aq[0][0], s00, 0,0,0);
    s00 = __builtin_amdgcn_mfma_f32_16x16x32_bf16(ak01, aq[0][1], s00, 0,0,0);
    s01 = __builtin_amdgcn_mfma_f32_16x16x32_bf16(ak10, aq[0][0], s01, 0,0,0);
    s01 = __builtin_amdgcn_mfma_f32_16x16x32_bf16(ak11, aq[0][1], s01, 0,0,0);
    s10 = __builtin_amdgcn_mfma_f32_16x16x32_bf16(ak00, aq[1][0], s10, 0,0,0);
    s10 = __builtin_amdgcn_mfma_f32_16x16x32_bf16(ak01, aq[1][1], s10, 0,0,0);
    s11 = __builtin_amdgcn_mfma_f32_16x16x32_bf16(ak10, aq[1][0], s11, 0,0,0);
    s11 = __builtin_amdgcn_mfma_f32_16x16x32_bf16(ak11, aq[1][1], s11, 0,0,0);
#pragma unroll
    for (int r = 0; r < 4; ++r) {
      z0 += __expf(s00[r] * 0.125f) + __expf(s01[r] * 0.125f);
      z1 += __expf(s10[r] * 0.125f) + __expf(s11[r] * 0.125f);
    }
  }
  z0 += __shfl_xor(z0, 16); z0 += __shfl_xor(z0, 32);
  z1 += __shfl_xor(z1, 16); z1 += __shfl_xor(z1, 32);
  if (lane < 16) {
    const size_t zb = ((size_t)(b * NQT2 + qt) * NCHA + c) * 128 + w * 32;
    Zp[zb + lane] = z0;
    Zp[zb + 16 + lane] = z1;
  }
}

// ---------- pass B: causal chunk partial; 128q x 256k tiles, no LDS ----------
__global__ __launch_bounds__(256, 3)
void passB_kernel(const short* __restrict__ Qb, const short* __restrict__ Kb,
                  const short* __restrict__ Vt, const float* __restrict__ Zp,
                  short* __restrict__ po, float* __restrict__ pws) {
  const int b = blockIdx.y;
  const int fwd = TILESB - 1 - blockIdx.x;   // ascending live-tile id
  int a = 0;
#pragma unroll
  for (int aa = 1; aa <= 15; ++aa) a += (fwd >= aa * (aa + 1)) ? 1 : 0;
  const int rem = fwd - a * (a + 1);
  const int odd = (rem >= a + 1) ? 1 : 0;
  const int qt = 2 * a + odd;
  const int c = rem - odd * (a + 1);
  const int q0 = qt * 128;
  const int c0 = c * KCHB;
  const int kend = min(c0 + KCHB, q0 + 128);

  const int t = threadIdx.x;
  const int w = t >> 6, lane = t & 63, g = lane >> 4, l15 = lane & 15;
  const int qbase = q0 + w * 32;
  const short* Qp = Qb + (size_t)b * T_ * H_;
  const short* Kp = Kb + (size_t)b * T_ * H_;
  const short* Vp = Vt + (size_t)b * H_ * T_;

  bf16x8 aq[2][2];
#pragma unroll
  for (int qs = 0; qs < 2; ++qs)
#pragma unroll
    for (int h = 0; h < 2; ++h)
      aq[qs][h] = *(const bf16x8*)&Qp[(size_t)(qbase + qs*16 + l15) * H_ + h*32 + 8*g];

  float zt0 = 0.f, zt1 = 0.f;
  {
    const size_t zb = (size_t)(b * NQT2 + qt) * NCHA;
#pragma unroll
    for (int cc = 0; cc < NCHA; ++cc) {
      zt0 += Zp[(zb + cc) * 128 + w * 32 + l15];
      zt1 += Zp[(zb + cc) * 128 + w * 32 + 16 + l15];
    }
  }
  const float zinv0 = 1.0f / zt0, zinv1 = 1.0f / zt1;
  const int qg0 = qbase + l15, qg1 = qbase + 16 + l15;

  f32x4 o[2][4] = {{{0,0,0,0},{0,0,0,0},{0,0,0,0},{0,0,0,0}},
                   {{0,0,0,0},{0,0,0,0},{0,0,0,0},{0,0,0,0}}};
  float ws0 = 0.f, ws1 = 0.f;
  const int krow = ((l15 >> 2) << 3) + (l15 & 3);

  for (int kt = c0; kt < kend; kt += 32) {
    const short* kr = Kp + (size_t)(kt + krow) * H_;
    const bf16x8 ak00 = *(const bf16x8*)(kr + 8 * g);
    const bf16x8 ak01 = *(const bf16x8*)(kr + 32 + 8 * g);
    const bf16x8 ak10 = *(const bf16x8*)(kr + 4 * H_ + 8 * g);
    const bf16x8 ak11 = *(const bf16x8*)(kr + 4 * H_ + 32 + 8 * g);
    f32x4 s00 = {0,0,0,0}, s01 = {0,0,0,0}, s10 = {0,0,0,0}, s11 = {0,0,0,0};
    s00 = __builtin_amdgcn_mfma_f32_16x16x32_bf16(ak00, aq[0][0], s00, 0,0,0);
    s00 = __builtin_amdgcn_mfma_f32_16x16x32_bf16(ak01, aq[0][1], s00, 0,0,0);
    s01 = __builtin_amdgcn_mfma_f32_16x16x32_bf16(ak10, aq[0][0], s01, 0,0,0);
    s01 = __builtin_amdgcn_mfma_f32_16x16x32_bf16(ak11, aq[0][1], s01, 0,0,0);
    s10 = __builtin_amdgcn_mfma_f32_16x16x32_bf16(ak00, aq[1][0], s10, 0,0,0);
    s10 = __builtin_amdgcn_mfma_f32_16x16x32_bf16(ak01, aq[1][1], s10, 0,0,0);
    s11 = __builtin_amdgcn_mfma_f32_16x16x32_bf16(ak10, aq[1][0], s11, 0,0,0);
    s11 = __builtin_amdgcn_mfma_f32_16x16x32_bf16(ak11, aq[1][1], s11, 0,0,0);
    bf16x8 wb0, wb1;
    if (kt + 31 <= qbase) {          // interior: no mask needed (all keys <= all q)
#pragma unroll
      for (int r = 0; r < 4; ++r) {
        const float w0 = __expf(__expf(s00[r] * 0.125f) * zinv0);
        const float w1 = __expf(__expf(s01[r] * 0.125f) * zinv0);
        ws0 += w0 + w1; wb0[r] = f2bf_rn(w0); wb0[4 + r] = f2bf_rn(w1);
        const float w2 = __expf(__expf(s10[r] * 0.125f) * zinv1);
        const float w3 = __expf(__expf(s11[r] * 0.125f) * zinv1);
        ws1 += w2 + w3; wb1[r] = f2bf_rn(w2); wb1[4 + r] = f2bf_rn(w3);
      }
    } else {                          // diagonal: per-element causal mask
#pragma unroll
      for (int r = 0; r < 4; ++r) {
        const int key0 = kt + 8 * g + r;
        const float w0 = (key0     <= qg0) ? __expf(__expf(s00[r] * 0.125f) * zinv0) : 0.f;
        const float w1 = (key0 + 4 <= qg0) ? __expf(__expf(s01[r] * 0.125f) * zinv0) : 0.f;
        ws0 += w0 + w1; wb0[r] = f2bf_rn(w0); wb0[4 + r] = f2bf_rn(w1);
        const float w2 = (key0     <= qg1) ? __expf(__expf(s10[r] * 0.125f) * zinv1) : 0.f;
        const float w3 = (key0 + 4 <= qg1) ? __expf(__expf(s11[r] * 0.125f) * zinv1) : 0.f;
        ws1 += w2 + w3; wb1[r] = f2bf_rn(w2); wb1[4 + r] = f2bf_rn(w3);
      }
    }
#pragma unroll
    for (int nt = 0; nt < 4; ++nt) {
      const bf16x8 av = *(const bf16x8*)&Vp[(size_t)(nt*16 + l15) * T_ + kt + 8*g];
      o[0][nt] = __builtin_amdgcn_mfma_f32_16x16x32_bf16(av, wb0, o[0][nt], 0,0,0);
      o[1][nt] = __builtin_amdgcn_mfma_f32_16x16x32_bf16(av, wb1, o[1][nt], 0,0,0);
    }
  }

  ws0 += __shfl_xor(ws0, 16); ws0 += __shfl_xor(ws0, 32);
  ws1 += __shfl_xor(ws1, 16); ws1 += __shfl_xor(ws1, 32);

  const size_t base = ((size_t)b * TILESB + fwd) * 128;
#pragma unroll
  for (int qs = 0; qs < 2; ++qs) {
    const size_t row = base + w * 32 + qs * 16 + l15;
#pragma unroll
    for (int nt = 0; nt < 4; ++nt) {
      short4 v;
      v.x = f2bf_rn(o[qs][nt][0]); v.y = f2bf_rn(o[qs][nt][1]);
      v.z = f2bf_rn(o[qs][nt][2]); v.w = f2bf_rn(o[qs][nt][3]);
      *(short4*)&po[row * 64 + nt * 16 + 4 * g] = v;
    }
  }
  if (lane < 16) {
    pws[base + w * 32 + lane] = ws0;
    pws[base + w * 32 + 16 + lane] = ws1;
  }
}

// ---------- combine: out = sum_c po / sum_c pws ----------
__global__ __launch_bounds__(256)
void combine_kernel(const short* __restrict__ po, const float* __restrict__ pws,
                    float* __restrict__ out) {
  const int qt = blockIdx.x, b = blockIdx.y;
  const int a = qt >> 1, odd = qt & 1;
  const int basef = a * (a + 1) + odd * (a + 1);
  const int nc = a + 1;
  for (int e = threadIdx.x; e < 2048; e += 256) {
    const int q = e >> 4, d4 = e & 15;
    float ax = 0.f, ay = 0.f, az = 0.f, aw = 0.f, wsr = 0.f;
    for (int cc = 0; cc < nc; ++cc) {
      const size_t row = ((size_t)b * TILESB + basef + cc) * 128 + q;
      const short4 v = *(const short4*)&po[row * 64 + d4 * 4];
      ax += bf2f(v.x); ay += bf2f(v.y); az += bf2f(v.z); aw += bf2f(v.w);
      wsr += pws[row];
    }
    const float inv = 1.0f / wsr;
    float4 rv = make_float4(ax * inv, ay * inv, az * inv, aw * inv);
    *(float4*)&out[((size_t)(b * T_ + qt * 128 + q)) * H_ + d4 * 4] = rv;
  }
}

extern "C" void kernel_launch(void* const* d_in, const int* in_sizes, int n_in,
                              void* d_out, int out_size, void* d_ws, size_t ws_size,
                              hipStream_t stream) {
  (void)in_sizes; (void)n_in; (void)out_size; (void)ws_size;
  const float* x  = (const float*)d_in[0];
  const float* wq = (const float*)d_in[1];
  const float* wk = (const float*)d_in[2];
  const float* wv = (const float*)d_in[3];

  char* ws = (char*)d_ws;
  short* wt  = (short*)(ws);                       // 384 KB
  short* Qb  = (short*)(ws + 0x0060000);           // 2 MB
  short* Kb  = (short*)(ws + 0x0260000);           // 2 MB
  short* Vt  = (short*)(ws + 0x0460000);           // 2 MB
  float* Zp  = (float*)(ws + 0x0660000);           // 512 KB: 4*32*8*128*4
  float* pws = (float*)(ws + 0x06E0000);           // 557 KB: 4*272*128*4
  short* po  = (short*)(ws + 0x0768000);           // 17.8 MB: 4*272*128*64*2
  float* outp = (float*)d_out;

  wtconv_kernel<<<192, 256, 0, stream>>>(wq, wk, wv, wt);
  proj_kernel<<<(B_ * T_) / 32, 256, 0, stream>>>(x, wt, Qb, Kb, Vt);
  passA_kernel<<<dim3(NQT2, NCHA, B_), 256, 0, stream>>>(Qb, Kb, Zp);
  passB_kernel<<<dim3(TILESB, B_), 256, 0, stream>>>(Qb, Kb, Vt, Zp, po, pws);
  combine_kernel<<<dim3(NQT2, B_), 256, 0, stream>>>(po, pws, outp);
}